// Round 4
// baseline (55.525 us; speedup 1.0000x reference)
//
#include <hip/hip_runtime.h>
#include <math.h>

#define BATCH 8
#define NN 2048
#define DD 128

typedef float vf4 __attribute__((ext_vector_type(4)));

// Kernel 1: per-row dual dot products. One 64-lane wave per row (B*N rows).
__global__ __launch_bounds__(256) void score_kernel(
    const float* __restrict__ x, const float* __restrict__ W,
    const float* __restrict__ bias,
    float* __restrict__ sl, float* __restrict__ sr) {
    int wave = (blockIdx.x * blockDim.x + threadIdx.x) >> 6;
    int lane = threadIdx.x & 63;
    if (wave >= BATCH * NN) return;
    const float* xr = x + (size_t)wave * DD;
    float x0 = xr[lane];
    float x1 = xr[lane + 64];
    float l = x0 * W[lane] + x1 * W[lane + 64];
    float r = x0 * W[DD + lane] + x1 * W[DD + lane + 64];
    #pragma unroll
    for (int off = 32; off; off >>= 1) {
        l += __shfl_xor(l, off, 64);
        r += __shfl_xor(r, off, 64);
    }
    if (lane == 0) {
        sl[wave] = l + bias[0];
        sr[wave] = r;
    }
}

// Kernel 2: out[b,i,j] = adj[b,i,j] * sigmoid(sl[b,i] + sr[b,j])
// Block k owns rows [8k, 8k+8). sr batch-slice (8 KB) + sl (8 floats)
// staged in LDS so the hot loop is exactly one global load + one LDS
// read + one global store per 16 B — same VMEM profile as a pure copy.
__global__ __launch_bounds__(256) void att_kernel(
    const float* __restrict__ adj, const float* __restrict__ sl,
    const float* __restrict__ sr, float* __restrict__ out) {
    __shared__ float s_sr[NN];
    __shared__ float s_sl[8];
    const int row0 = blockIdx.x * 8;
    const int b = row0 >> 11;                    // batch (8 rows never straddle)
    const int tid = threadIdx.x;

    // Stage sr[b,:] (512 vf4) and sl[row0..row0+8) into LDS.
    const vf4* srb = (const vf4*)(sr + (size_t)b * NN);
    ((vf4*)s_sr)[tid]       = srb[tid];
    ((vf4*)s_sr)[256 + tid] = srb[256 + tid];
    if (tid < 8) s_sl[tid] = sl[row0 + tid];
    __syncthreads();

    #pragma unroll
    for (int r = 0; r < 8; ++r) {
        const size_t row = row0 + r;
        const float slv = s_sl[r];
        const vf4* arow = (const vf4*)(adj + row * NN);
        vf4* orow = (vf4*)(out + row * NN);
        #pragma unroll
        for (int h = 0; h < 2; ++h) {
            const int j4 = h * 256 + tid;
            const vf4 s4 = ((const vf4*)s_sr)[j4];
            const vf4 a = __builtin_nontemporal_load(arow + j4);
            vf4 o;
            o.x = a.x * __builtin_amdgcn_rcpf(1.0f + __expf(-(slv + s4.x)));
            o.y = a.y * __builtin_amdgcn_rcpf(1.0f + __expf(-(slv + s4.y)));
            o.z = a.z * __builtin_amdgcn_rcpf(1.0f + __expf(-(slv + s4.z)));
            o.w = a.w * __builtin_amdgcn_rcpf(1.0f + __expf(-(slv + s4.w)));
            __builtin_nontemporal_store(o, orow + j4);
        }
    }
}

extern "C" void kernel_launch(void* const* d_in, const int* in_sizes, int n_in,
                              void* d_out, int out_size, void* d_ws, size_t ws_size,
                              hipStream_t stream) {
    const float* x   = (const float*)d_in[0];   // (8,2048,128)
    const float* adj = (const float*)d_in[1];   // (8,2048,2048)
    const float* W   = (const float*)d_in[2];   // (256,)
    const float* b   = (const float*)d_in[3];   // (1,)
    float* out = (float*)d_out;

    float* sl = (float*)d_ws;                   // 16384 floats
    float* sr = sl + BATCH * NN;                // 16384 floats

    // Kernel 1: 16384 waves, one per row
    int rows = BATCH * NN;
    int blocks1 = rows / 4;                     // 4096 blocks x 4 waves
    score_kernel<<<blocks1, 256, 0, stream>>>(x, W, b, sl, sr);

    // Kernel 2: 2048 blocks x 8 rows each (exact cover of 16384 rows)
    att_kernel<<<BATCH * NN / 8, 256, 0, stream>>>(adj, sl, sr, out);
}

// Round 5
// 52.984 us; speedup vs baseline: 1.0480x; 1.0480x over previous
//
#include <hip/hip_runtime.h>
#include <math.h>

#define BATCH 8
#define NN 2048
#define DD 128

typedef float vf4 __attribute__((ext_vector_type(4)));

// Kernel 1: per-row dual dot products. One 64-lane wave per row (B*N rows).
__global__ __launch_bounds__(256) void score_kernel(
    const float* __restrict__ x, const float* __restrict__ W,
    const float* __restrict__ bias,
    float* __restrict__ sl, float* __restrict__ sr) {
    int wave = (blockIdx.x * blockDim.x + threadIdx.x) >> 6;
    int lane = threadIdx.x & 63;
    if (wave >= BATCH * NN) return;
    const float* xr = x + (size_t)wave * DD;
    float x0 = xr[lane];
    float x1 = xr[lane + 64];
    float l = x0 * W[lane] + x1 * W[lane + 64];
    float r = x0 * W[DD + lane] + x1 * W[DD + lane + 64];
    #pragma unroll
    for (int off = 32; off; off >>= 1) {
        l += __shfl_xor(l, off, 64);
        r += __shfl_xor(r, off, 64);
    }
    if (lane == 0) {
        sl[wave] = l + bias[0];
        sr[wave] = r;
    }
}

// Kernel 2: out[b,i,j] = adj[b,i,j] * sigmoid(sl[b,i] + sr[b,j])
// Block k owns rows [8k, 8k+8). sr batch-slice (8 KB) + sl (8 floats)
// staged in LDS. Plain (cached) loads/stores — A/B vs round 4's
// nontemporal version, which sat ~17% below the copy-BW ceiling.
__global__ __launch_bounds__(256) void att_kernel(
    const float* __restrict__ adj, const float* __restrict__ sl,
    const float* __restrict__ sr, float* __restrict__ out) {
    __shared__ float s_sr[NN];
    __shared__ float s_sl[8];
    const int row0 = blockIdx.x * 8;
    const int b = row0 >> 11;                    // batch (8 rows never straddle)
    const int tid = threadIdx.x;

    // Stage sr[b,:] (512 vf4) and sl[row0..row0+8) into LDS.
    const vf4* srb = (const vf4*)(sr + (size_t)b * NN);
    ((vf4*)s_sr)[tid]       = srb[tid];
    ((vf4*)s_sr)[256 + tid] = srb[256 + tid];
    if (tid < 8) s_sl[tid] = sl[row0 + tid];
    __syncthreads();

    #pragma unroll
    for (int r = 0; r < 8; ++r) {
        const size_t row = row0 + r;
        const float slv = s_sl[r];
        const vf4* arow = (const vf4*)(adj + row * NN);
        vf4* orow = (vf4*)(out + row * NN);
        #pragma unroll
        for (int h = 0; h < 2; ++h) {
            const int j4 = h * 256 + tid;
            const vf4 s4 = ((const vf4*)s_sr)[j4];
            const vf4 a = arow[j4];
            vf4 o;
            o.x = a.x * __builtin_amdgcn_rcpf(1.0f + __expf(-(slv + s4.x)));
            o.y = a.y * __builtin_amdgcn_rcpf(1.0f + __expf(-(slv + s4.y)));
            o.z = a.z * __builtin_amdgcn_rcpf(1.0f + __expf(-(slv + s4.z)));
            o.w = a.w * __builtin_amdgcn_rcpf(1.0f + __expf(-(slv + s4.w)));
            orow[j4] = o;
        }
    }
}

extern "C" void kernel_launch(void* const* d_in, const int* in_sizes, int n_in,
                              void* d_out, int out_size, void* d_ws, size_t ws_size,
                              hipStream_t stream) {
    const float* x   = (const float*)d_in[0];   // (8,2048,128)
    const float* adj = (const float*)d_in[1];   // (8,2048,2048)
    const float* W   = (const float*)d_in[2];   // (256,)
    const float* b   = (const float*)d_in[3];   // (1,)
    float* out = (float*)d_out;

    float* sl = (float*)d_ws;                   // 16384 floats
    float* sr = sl + BATCH * NN;                // 16384 floats

    // Kernel 1: 16384 waves, one per row
    int rows = BATCH * NN;
    int blocks1 = rows / 4;                     // 4096 blocks x 4 waves
    score_kernel<<<blocks1, 256, 0, stream>>>(x, W, b, sl, sr);

    // Kernel 2: 2048 blocks x 8 rows each (exact cover of 16384 rows)
    att_kernel<<<BATCH * NN / 8, 256, 0, stream>>>(adj, sl, sr, out);
}